// Round 5
// baseline (150.047 us; speedup 1.0000x reference)
//
#include <hip/hip_runtime.h>

#define Bn 8
#define Ln 256
#define Dn 128
#define Hn 6
#define En 32
#define WXROW (Hn + 2*Dn + En)   // 294
#define ROWS 4                   // i-rows per k_gcn2 block

// -------- Kernel 0: adj_avg precompute --------
// grid 512, 256 thr: one float4 of adj_avg per thread
__global__ __launch_bounds__(256) void k_avg(
    const float* __restrict__ wadj, float* __restrict__ avg)
{
    const int g = blockIdx.x * 256 + threadIdx.x;    // float4 index into (B,L,L)
    const int j4 = g & 63;
    const int i  = (g >> 6) & 255;
    const int b  = g >> 14;
    const float4* w4 = (const float4*)wadj;
    float4 s = {0.f, 0.f, 0.f, 0.f};
    #pragma unroll
    for (int h = 0; h < Hn; ++h) {
        const float4 v = w4[(((size_t)b * Hn + h) * Ln + i) * (Ln / 4) + j4];
        s.x += v.x; s.y += v.y; s.z += v.z; s.w += v.w;
    }
    const float inv_h = 1.0f / 6.0f;
    s.x *= inv_h; s.y *= inv_h; s.z *= inv_h; s.w *= inv_h;
    ((float4*)avg)[g] = s;
}

// -------- Kernel 1: gcn + out + n1/n2 --------
// grid = B * (L/ROWS) = 512 blocks, 512 threads (8 waves)
__global__ __launch_bounds__(512) void k_gcn2(
    const float* __restrict__ x, const float* __restrict__ avg,
    const float* __restrict__ W_w, const float* __restrict__ W_b,
    const float* __restrict__ Wx_w,
    const float* __restrict__ Wxx_w, const float* __restrict__ Wxx_b,
    float* __restrict__ out, float* __restrict__ n1_ws, float* __restrict__ n2_ws)
{
    __shared__ float adj[ROWS][Ln];        // 4 KB
    __shared__ float part[16][ROWS][Dn];   // 32 KB
    __shared__ float t_s[ROWS][Dn];        // 2 KB
    __shared__ float g_s[ROWS][Dn];        // 2 KB

    const int t  = threadIdx.x;
    const int b  = blockIdx.x >> 6;
    const int i0 = (blockIdx.x & 63) * ROWS;

    // A) load adj_avg rows i0..i0+3  (256 float4, threads t<256)
    if (t < 256)
        ((float4*)&adj[0][0])[t] = ((const float4*)avg)[((size_t)b << 14) + (i0 << 6) + t];
    __syncthreads();

    // B) partial t: q = t>>5 (0..15) takes js [q*16, q*16+16); d4 = t&31
    {
        const int q  = t >> 5;
        const int d4 = t & 31;
        float4 acc[ROWS];
        #pragma unroll
        for (int r = 0; r < ROWS; ++r) acc[r] = {0.f, 0.f, 0.f, 0.f};
        const float4* xp4  = (const float4*)(x + (size_t)b * Ln * Dn) + d4;
        const float4* adj4 = (const float4*)&adj[0][0];
        #pragma unroll
        for (int jj4 = 0; jj4 < 4; ++jj4) {
            const int j = q * 16 + jj4 * 4;
            const float4 xv0 = xp4[(size_t)(j + 0) * 32];
            const float4 xv1 = xp4[(size_t)(j + 1) * 32];
            const float4 xv2 = xp4[(size_t)(j + 2) * 32];
            const float4 xv3 = xp4[(size_t)(j + 3) * 32];
            #pragma unroll
            for (int r = 0; r < ROWS; ++r) {
                const float4 a = adj4[r * 64 + (j >> 2)];
                float4 v = acc[r];
                v.x = fmaf(a.x, xv0.x, v.x); v.y = fmaf(a.x, xv0.y, v.y);
                v.z = fmaf(a.x, xv0.z, v.z); v.w = fmaf(a.x, xv0.w, v.w);
                v.x = fmaf(a.y, xv1.x, v.x); v.y = fmaf(a.y, xv1.y, v.y);
                v.z = fmaf(a.y, xv1.z, v.z); v.w = fmaf(a.y, xv1.w, v.w);
                v.x = fmaf(a.z, xv2.x, v.x); v.y = fmaf(a.z, xv2.y, v.y);
                v.z = fmaf(a.z, xv2.z, v.z); v.w = fmaf(a.z, xv2.w, v.w);
                v.x = fmaf(a.w, xv3.x, v.x); v.y = fmaf(a.w, xv3.y, v.y);
                v.z = fmaf(a.w, xv3.z, v.z); v.w = fmaf(a.w, xv3.w, v.w);
                acc[r] = v;
            }
        }
        #pragma unroll
        for (int r = 0; r < ROWS; ++r)
            ((float4*)&part[q][r][0])[d4] = acc[r];
    }
    __syncthreads();

    // C) combine 16 j-slices: rr = t>>7 (0..3), d = t&127
    {
        const int rr = t >> 7, d = t & 127;
        float s = 0.f;
        #pragma unroll
        for (int q = 0; q < 16; ++q) s += part[q][rr][d];
        t_s[rr][d] = s;
    }
    __syncthreads();

    // D) g partial: s = t>>7 (0..3) takes c in [s*32, s*32+32); d = t&127
    {
        const int s = t >> 7, d = t & 127, c0 = s * 32;
        const float4* wr = (const float4*)(W_w + (size_t)d * Dn + c0);
        float acc[ROWS] = {0.f, 0.f, 0.f, 0.f};
        #pragma unroll
        for (int c4 = 0; c4 < 8; ++c4) {
            const float4 w = wr[c4];
            #pragma unroll
            for (int r = 0; r < ROWS; ++r) {
                const float4 u = ((const float4*)&t_s[r][c0])[c4];
                float a = acc[r];
                a = fmaf(u.x, w.x, a); a = fmaf(u.y, w.y, a);
                a = fmaf(u.z, w.z, a); a = fmaf(u.w, w.w, a);
                acc[r] = a;
            }
        }
        #pragma unroll
        for (int r = 0; r < ROWS; ++r) part[s][r][d] = acc[r];
    }
    __syncthreads();

    // E) combine + bias + relu
    {
        const int rr = t >> 7, d = t & 127;
        const float v = part[0][rr][d] + part[1][rr][d] + part[2][rr][d]
                      + part[3][rr][d] + W_b[d];
        g_s[rr][d] = fmaxf(v, 0.f);
    }
    __syncthreads();

    // F) out partial with Wxx
    {
        const int s = t >> 7, d = t & 127, c0 = s * 32;
        const float4* wr = (const float4*)(Wxx_w + (size_t)d * Dn + c0);
        float acc[ROWS] = {0.f, 0.f, 0.f, 0.f};
        #pragma unroll
        for (int c4 = 0; c4 < 8; ++c4) {
            const float4 w = wr[c4];
            #pragma unroll
            for (int r = 0; r < ROWS; ++r) {
                const float4 u = ((const float4*)&g_s[r][c0])[c4];
                float a = acc[r];
                a = fmaf(u.x, w.x, a); a = fmaf(u.y, w.y, a);
                a = fmaf(u.z, w.z, a); a = fmaf(u.w, w.w, a);
                acc[r] = a;
            }
        }
        __syncthreads();   // part reused below; D->F read older part, safe to wait here
        #pragma unroll
        for (int r = 0; r < ROWS; ++r) part[s][r][t & 127] = acc[r];
    }
    __syncthreads();

    // G) combine + bias -> out
    {
        const int rr = t >> 7, d = t & 127;
        const float v = part[0][rr][d] + part[1][rr][d] + part[2][rr][d]
                      + part[3][rr][d] + Wxx_b[d];
        out[((size_t)b * Ln + (i0 + rr)) * Dn + d] = v;
    }

    // H) n1/n2: 48 dot-products of length 128 (reads g_s, unchanged since E)
    if (t < ROWS * 2 * Hn) {
        const int r  = t / (2 * Hn);
        const int kk = t % (2 * Hn);
        const int k  = (kk < Hn) ? kk : (kk - Hn);
        const bool isn2 = (kk >= Hn);
        const float* wrow = Wx_w + (size_t)k * WXROW + Hn + (isn2 ? Dn : 0);
        float acc = 0.f;
        #pragma unroll 8
        for (int c = 0; c < Dn; ++c)
            acc = fmaf(g_s[r][c], wrow[c], acc);
        const size_t idx = ((size_t)b * Hn + k) * Ln + (i0 + r);
        if (isn2) n2_ws[idx] = acc;
        else      n1_ws[idx] = acc;
    }
}

// -------- Kernel 2: new_adj (chunked LDS: 2 j-halves) --------
// grid = B*L blocks (b,i), 256 threads
#define EPAD 33
__global__ __launch_bounds__(256) void k_adj(
    const float* __restrict__ wadj, const float* __restrict__ e,
    const float* __restrict__ Wx_w, const float* __restrict__ Wx_b,
    const float* __restrict__ n1_ws, const float* __restrict__ n2_ws,
    float* __restrict__ new_adj)
{
    __shared__ float e_lds[128 * EPAD];  // 16.5 KB
    __shared__ float Wa_s[Hn][Hn];
    __shared__ float We_s[Hn][En];
    __shared__ float bias_n1[Hn];

    const int t = threadIdx.x;
    const int b = blockIdx.x >> 8;
    const int i = blockIdx.x & 255;

    if (t < Hn * Hn) {
        const int k = t / Hn, h = t % Hn;
        Wa_s[k][h] = Wx_w[(size_t)k * WXROW + h];
    }
    if (t >= 64 && t < 64 + Hn * En) {
        const int q = t - 64, k = q / En, c = q % En;
        We_s[k][c] = Wx_w[(size_t)k * WXROW + Hn + 2 * Dn + c];
    }
    if (t >= 32 && t < 32 + Hn) {
        const int k = t - 32;
        bias_n1[k] = Wx_b[k] + n1_ws[((size_t)b * Hn + k) * Ln + i];
    }

    const float4* ep4 = (const float4*)(e + (((size_t)b * Ln + i) * Ln) * En);
    const int s  = t >> 7;          // k-group: 0 -> k 0..2, 1 -> k 3..5
    const int jl = t & 127;         // local j within chunk

    #pragma unroll
    for (int cH = 0; cH < 2; ++cH) {
        __syncthreads();            // protect e_lds from previous chunk's readers
        // stage 128 rows x 32 floats = 1024 float4, 4 per thread, coalesced
        #pragma unroll
        for (int p = 0; p < 4; ++p) {
            const int idx = t + p * 256;
            const float4 v = ep4[cH * 1024 + idx];
            const int j = idx >> 3;
            const int c = (idx & 7) * 4;
            float* dst = &e_lds[j * EPAD + c];
            dst[0] = v.x; dst[1] = v.y; dst[2] = v.z; dst[3] = v.w;
        }
        __syncthreads();

        const int j = cH * 128 + jl;

        float wv[Hn];
        #pragma unroll
        for (int h = 0; h < Hn; ++h)
            wv[h] = wadj[(((size_t)b * Hn + h) * Ln + i) * Ln + j];

        const float* ev = &e_lds[jl * EPAD];

        #pragma unroll
        for (int kq = 0; kq < 3; ++kq) {
            const int k = s * 3 + kq;
            float acc = bias_n1[k] + n2_ws[((size_t)b * Hn + k) * Ln + j];
            #pragma unroll
            for (int h = 0; h < Hn; ++h)
                acc = fmaf(wv[h], Wa_s[k][h], acc);
            #pragma unroll
            for (int c = 0; c < En; ++c)
                acc = fmaf(ev[c], We_s[k][c], acc);
            new_adj[(((size_t)b * Hn + k) * Ln + i) * Ln + j] = acc;
        }
    }
}

extern "C" void kernel_launch(void* const* d_in, const int* in_sizes, int n_in,
                              void* d_out, int out_size, void* d_ws, size_t ws_size,
                              hipStream_t stream) {
    const float* x      = (const float*)d_in[0];
    const float* wadj   = (const float*)d_in[1];
    const float* e      = (const float*)d_in[2];
    const float* W_w    = (const float*)d_in[3];
    const float* W_b    = (const float*)d_in[4];
    const float* Wx_w   = (const float*)d_in[5];
    const float* Wx_b   = (const float*)d_in[6];
    const float* Wxx_w  = (const float*)d_in[7];
    const float* Wxx_b  = (const float*)d_in[8];

    float* out      = (float*)d_out;                   // (B,L,D)
    float* new_adj  = out + (size_t)Bn * Ln * Dn;      // (B,H,L,L)

    float* n1_ws = (float*)d_ws;                          // (B,H,L)
    float* n2_ws = n1_ws + (size_t)Bn * Hn * Ln;          // (B,H,L)
    float* avg   = n2_ws + (size_t)Bn * Hn * Ln;          // (B,L,L), 16B-aligned

    k_avg<<<(Bn * Ln * Ln / 4) / 256, 256, 0, stream>>>(wadj, avg);
    k_gcn2<<<Bn * (Ln / ROWS), 512, 0, stream>>>(x, avg, W_w, W_b, Wx_w,
                                                 Wxx_w, Wxx_b, out, n1_ws, n2_ws);
    k_adj<<<Bn * Ln, 256, 0, stream>>>(wadj, e, Wx_w, Wx_b, n1_ws, n2_ws, new_adj);
}